// Round 5
// baseline (33.894 us; speedup 1.0000x reference)
//
#include <hip/hip_runtime.h>

#define NBITS 13
#define DMODEL 1024
#define PPB 16  // positions per block: 16 x 4 KB = 64 KB contiguous output/block

typedef float v4f __attribute__((ext_vector_type(4)));

// out[p, d] = sum over set bits b of x[p] of emb[b, d]
// One block = 16 consecutive positions, fully unrolled. Fresh accumulator per
// position (no vmcnt register-reuse stalls), nontemporal stores (output is
// write-once, never re-read -> skip L2 allocate).
__global__ __launch_bounds__(256) void bpe_kernel(const int* __restrict__ x,
                                                  const float* __restrict__ emb,
                                                  float* __restrict__ out,
                                                  int npos) {
    const int t = threadIdx.x;  // owns columns 4t..4t+3

    // 13 x float4 = 52 VGPRs of emb slice, loaded once per block (L2-hit).
    v4f frag[NBITS];
#pragma unroll
    for (int b = 0; b < NBITS; ++b) {
        frag[b] = *reinterpret_cast<const v4f*>(emb + b * DMODEL + t * 4);
    }

    const int base = blockIdx.x * PPB;

    if (base + PPB <= npos) {
        // All 16 x values up front: uniform addresses -> scalar dwordx4 loads.
        int xv[PPB];
#pragma unroll
        for (int i = 0; i < PPB; i += 4) {
            const int4 v = *reinterpret_cast<const int4*>(x + base + i);
            xv[i + 0] = v.x;
            xv[i + 1] = v.y;
            xv[i + 2] = v.z;
            xv[i + 3] = v.w;
        }

        float* o = out + (size_t)base * DMODEL + (size_t)(t * 4);
#pragma unroll
        for (int i = 0; i < PPB; ++i) {
            const int v = xv[i];
            v4f acc = {0.f, 0.f, 0.f, 0.f};
#pragma unroll
            for (int b = 0; b < NBITS; ++b) {
                // 1.0f/0.0f multiplier via uniform bit select (s_cselect).
                const float m = __int_as_float(((v >> b) & 1) ? 0x3f800000 : 0);
                acc.x = fmaf(m, frag[b].x, acc.x);
                acc.y = fmaf(m, frag[b].y, acc.y);
                acc.z = fmaf(m, frag[b].z, acc.z);
                acc.w = fmaf(m, frag[b].w, acc.w);
            }
            // Nontemporal: write-once stream, bypass L2 allocate.
            __builtin_nontemporal_store(acc,
                reinterpret_cast<v4f*>(o + (size_t)i * DMODEL));
        }
    } else {
        // Tail (npos % 16 != 0) — not hit for npos=32768.
        for (int p = base; p < npos; ++p) {
            const int v = x[p];
            v4f acc = {0.f, 0.f, 0.f, 0.f};
#pragma unroll
            for (int b = 0; b < NBITS; ++b) {
                const float m = __int_as_float(((v >> b) & 1) ? 0x3f800000 : 0);
                acc.x = fmaf(m, frag[b].x, acc.x);
                acc.y = fmaf(m, frag[b].y, acc.y);
                acc.z = fmaf(m, frag[b].z, acc.z);
                acc.w = fmaf(m, frag[b].w, acc.w);
            }
            __builtin_nontemporal_store(acc,
                reinterpret_cast<v4f*>(out + (size_t)p * DMODEL + (size_t)(t * 4)));
        }
    }
}

extern "C" void kernel_launch(void* const* d_in, const int* in_sizes, int n_in,
                              void* d_out, int out_size, void* d_ws, size_t ws_size,
                              hipStream_t stream) {
    const int* x = (const int*)d_in[0];        // (4, 8192) int32, flat 32768
    const float* emb = (const float*)d_in[1];  // (13, 1024) float32
    float* out = (float*)d_out;                // (4, 8192, 1024) float32

    const int npos = in_sizes[0];  // 32768

    const int grid = (npos + PPB - 1) / PPB;   // 2048 blocks for npos=32768
    bpe_kernel<<<grid, 256, 0, stream>>>(x, emb, out, npos);
}

// Round 6
// 27.574 us; speedup vs baseline: 1.2292x; 1.2292x over previous
//
#include <hip/hip_runtime.h>

#define NBITS 13
#define DMODEL 1024
#define PPB 32  // positions per block: 32 x 4 KB = 128 KB contiguous output/block

typedef float v4f __attribute__((ext_vector_type(4)));

// out[p, d] = sum over set bits b of x[p] of emb[b, d]
// One block = 32 consecutive positions, fully unrolled. Fresh accumulator per
// position -> stores are fire-and-forget (no vmcnt register-reuse stalls).
// Regular (cached) stores: L2 write-combining is what gets us to HBM peak
// (nontemporal measured -27% in R5).
__global__ __launch_bounds__(256) void bpe_kernel(const int* __restrict__ x,
                                                  const float* __restrict__ emb,
                                                  float* __restrict__ out,
                                                  int npos) {
    const int t = threadIdx.x;  // owns columns 4t..4t+3

    // 13 x float4 = 52 VGPRs of emb slice, loaded once per block.
    v4f frag[NBITS];
#pragma unroll
    for (int b = 0; b < NBITS; ++b) {
        frag[b] = *reinterpret_cast<const v4f*>(emb + b * DMODEL + t * 4);
    }

    const int base = blockIdx.x * PPB;

    if (base + PPB <= npos) {
        // All 32 x values up front: uniform addresses -> scalar dwordx4 loads.
        int xv[PPB];
#pragma unroll
        for (int i = 0; i < PPB; i += 4) {
            const int4 v = *reinterpret_cast<const int4*>(x + base + i);
            xv[i + 0] = v.x;
            xv[i + 1] = v.y;
            xv[i + 2] = v.z;
            xv[i + 3] = v.w;
        }

        float* o = out + (size_t)base * DMODEL + (size_t)(t * 4);
#pragma unroll
        for (int i = 0; i < PPB; ++i) {
            const int v = xv[i];
            v4f acc = {0.f, 0.f, 0.f, 0.f};
#pragma unroll
            for (int b = 0; b < NBITS; ++b) {
                // 1.0f/0.0f multiplier via uniform bit select (s_cselect).
                const float m = __int_as_float(((v >> b) & 1) ? 0x3f800000 : 0);
                acc.x = fmaf(m, frag[b].x, acc.x);
                acc.y = fmaf(m, frag[b].y, acc.y);
                acc.z = fmaf(m, frag[b].z, acc.z);
                acc.w = fmaf(m, frag[b].w, acc.w);
            }
            *reinterpret_cast<v4f*>(o + (size_t)i * DMODEL) = acc;
        }
    } else {
        // Tail (npos % 32 != 0) — not hit for npos=32768.
        for (int p = base; p < npos; ++p) {
            const int v = x[p];
            v4f acc = {0.f, 0.f, 0.f, 0.f};
#pragma unroll
            for (int b = 0; b < NBITS; ++b) {
                const float m = __int_as_float(((v >> b) & 1) ? 0x3f800000 : 0);
                acc.x = fmaf(m, frag[b].x, acc.x);
                acc.y = fmaf(m, frag[b].y, acc.y);
                acc.z = fmaf(m, frag[b].z, acc.z);
                acc.w = fmaf(m, frag[b].w, acc.w);
            }
            *reinterpret_cast<v4f*>(out + (size_t)p * DMODEL + (size_t)(t * 4)) = acc;
        }
    }
}

extern "C" void kernel_launch(void* const* d_in, const int* in_sizes, int n_in,
                              void* d_out, int out_size, void* d_ws, size_t ws_size,
                              hipStream_t stream) {
    const int* x = (const int*)d_in[0];        // (4, 8192) int32, flat 32768
    const float* emb = (const float*)d_in[1];  // (13, 1024) float32
    float* out = (float*)d_out;                // (4, 8192, 1024) float32

    const int npos = in_sizes[0];  // 32768

    const int grid = (npos + PPB - 1) / PPB;   // 1024 blocks for npos=32768
    bpe_kernel<<<grid, 256, 0, stream>>>(x, emb, out, npos);
}